// Round 16
// baseline (124.241 us; speedup 1.0000x reference)
//
#include <hip/hip_runtime.h>
#include <hip/hip_bf16.h>
#include <cstdint>
#include <math.h>

#define D_DIM 1024
#define TAU_INV 10.0f
// K stored as e4m3(64 * k_hat): acc = 4096 * sim -> exp(acc * TAU_INV/4096)
#define EXP_SCALE (TAU_INV / 4096.0f)
#define BK 64                  // 64 fp8 = 64 B per row chunk
#define NT (D_DIM / BK)        // 16 K-tiles
#define BM 128                 // tile rows
#define BN 128                 // tile cols
#define SLOT 16384             // ring slot: A 8K + B 8K
#define NB 64                  // 8192 / 128 row-blocks

typedef float f32x4 __attribute__((ext_vector_type(4)));
typedef long  l64x2 __attribute__((ext_vector_type(2)));

#define VMCNT(n) asm volatile("s_waitcnt vmcnt(" #n ")" ::: "memory")
#define LGKM0()  asm volatile("s_waitcnt lgkmcnt(0)" ::: "memory")
#define BAR() do { asm volatile("" ::: "memory"); \
                   __builtin_amdgcn_s_barrier();  \
                   asm volatile("" ::: "memory"); } while (0)

__device__ __forceinline__ float wave_reduce_add(float v) {
#pragma unroll
    for (int off = 32; off > 0; off >>= 1) v += __shfl_xor(v, off, 64);
    return v;
}

// ---- Kernel A (fused): normalize -> fp8 K (x64 pre-scale, INTERLEAVED),
//      positives, zero rowsum.
// Interleaved row layout (R14-verified): within each 64B K-tile chunk, 8B
// chunks ordered [g0h0][g0h1]...[g3h1] so a GEMM lane's full K=64 fragment is
// one contiguous 16B slot. Thread t (logical k = 4t..4t+3) -> physical word
// w = (t>>4)*16 + ((t>>1)&3)*4 + ((t>>3)&1)*2 + (t&1).
__global__ __launch_bounds__(256)
void norm_pos_kernel(const float* __restrict__ zi, const float* __restrict__ zj,
                     unsigned int* __restrict__ Kf, float* __restrict__ rowsum,
                     float* __restrict__ pos, int n_half) {
    const int i = blockIdx.x;
    const int t = threadIdx.x;                 // 256 threads x 4 floats = 1024
    float4 a = reinterpret_cast<const float4*>(zi + (size_t)i * D_DIM)[t];
    float4 b = reinterpret_cast<const float4*>(zj + (size_t)i * D_DIM)[t];
    float ssa = a.x*a.x + a.y*a.y + a.z*a.z + a.w*a.w;
    float ssb = b.x*b.x + b.y*b.y + b.z*b.z + b.w*b.w;
    float dab = a.x*b.x + a.y*b.y + a.z*b.z + a.w*b.w;
    ssa = wave_reduce_add(ssa);
    ssb = wave_reduce_add(ssb);
    dab = wave_reduce_add(dab);
    __shared__ float wsa[4], wsb[4], wsd[4];
    if ((t & 63) == 0) { wsa[t>>6] = ssa; wsb[t>>6] = ssb; wsd[t>>6] = dab; }
    __syncthreads();
    const float inva = 1.0f / sqrtf(wsa[0] + wsa[1] + wsa[2] + wsa[3]);
    const float invb = 1.0f / sqrtf(wsb[0] + wsb[1] + wsb[2] + wsb[3]);
    const float sa = inva * 64.0f;             // x64: keeps e4m3 in normal range
    const float sb = invb * 64.0f;
    unsigned int ua = 0, ub = 0;
    ua = __builtin_amdgcn_cvt_pk_fp8_f32(a.x * sa, a.y * sa, ua, false);
    ua = __builtin_amdgcn_cvt_pk_fp8_f32(a.z * sa, a.w * sa, ua, true);
    ub = __builtin_amdgcn_cvt_pk_fp8_f32(b.x * sb, b.y * sb, ub, false);
    ub = __builtin_amdgcn_cvt_pk_fp8_f32(b.z * sb, b.w * sb, ub, true);
    const int w = (t >> 4) * 16 + ((t >> 1) & 3) * 4 + ((t >> 3) & 1) * 2 + (t & 1);
    Kf[(size_t)i * 256 + w] = ua;                          // 1024 B row = 256 u32
    Kf[(size_t)(i + n_half) * 256 + w] = ub;
    if (t == 0) {
        pos[i] = (wsd[0] + wsd[1] + wsd[2] + wsd[3]) * inva * invb;
        rowsum[i] = 0.0f;
        rowsum[i + n_half] = 0.0f;
    }
}

// ---- Kernel B: triangular 128x128 tiles, 8 waves of 64x32, 3 blocks/CU -----
// R15 falsified "smaller tiles alone shrink the tail": job_time is invariant
// to tile size at fixed per-wave geometry. Config B shrinks per-wave work:
// 8 waves (2M x 4N) of 64x32 = acc[4][2]; per K-tile per wave 16 MFMA +
// 6 ds_read_b128. Per CU (3 blocks, 24 waves): MFMA 1862 cyc vs LDS 1728 cyc
// per K-tile -> MFMA-bound; job = 16 K-tiles ~ 12.4 us ideal. 2080 jobs on
// 768 slots -> 3 rounds, tax 1.11x (was 1.45x).
// Schedule = proven 1-barrier discipline (race-free since R4):
//   6 b128 frag reads (interleaved-fp8, 0-conflict R7 pattern)
//   stage_all(t+2)  [2 gloads/thread: A 1 issue + B 1 issue]
//   8 MFMA k-half lo ; LGKM0 ; VMCNT(2) ; BAR ; 8 MFMA k-half hi
// Residency: VMCNT(2)@t leaves only stage(t+2) -> BAR publishes t+1.
// Prologue: stage 0,1 (4 loads); VMCNT(2) -> tile 0 resident.
// Tail: t==NT-2 VMCNT(0); t==NT-1 no wait/BAR.
// diag (bx==by): row-reduction only, exact diagonal zeroed; else row+col.
__global__ __launch_bounds__(512, 6)
void simclr_gemm_kernel(const unsigned char* __restrict__ Kmat,
                        float* __restrict__ rowsum, int n_total) {
    __shared__ char lds[49152];

    const int tid  = threadIdx.x;
    const int lane = tid & 63;
    const int wave = tid >> 6;          // 0..7
    const int wr = wave >> 2;           // 0..1  (A rows wr*64)
    const int wc = wave & 3;            // 0..3  (B cols wc*32)
    const int kgrp = lane >> 4;         // 16B fragment slot within 64B row

    // bijective XCD swizzle: nwg = 2080 = 8 * 260
    const int wg = (blockIdx.x & 7) * 260 + (blockIdx.x >> 3);

    // decode wg -> (by, bx): by <= bx < NB (row-major triangular)
    int by = 0, start = 0;
    while (wg >= start + (NB - by)) { start += NB - by; ++by; }
    const int bx = by + (wg - start);
    const bool diag = (bx == by);
    const int rowbase = by * BM;
    const int colbase = bx * BN;

    const char* gK = reinterpret_cast<const char*>(Kmat);
    const int srow = tid >> 2;                          // 0..127 per 8KB issue
    const int sswz = (tid & 3) ^ ((srow >> 1) & 3);     // inverse-swizzled slot

    // stage full K-tile tt into ring slot tt%3: A 1 issue + B 1 issue
    auto stage_all = [&](int tt) {
        const int s = tt % 3;
        const size_t kbyte = (size_t)tt * BK;           // 64 B per row chunk
        const char* srcA = gK + (size_t)(rowbase + srow) * D_DIM + kbyte + sswz * 16;
        __builtin_amdgcn_global_load_lds(
            (const __attribute__((address_space(1))) void*)srcA,
            (__attribute__((address_space(3))) void*)(lds + s * SLOT + tid * 16),
            16, 0, 0);
        const char* srcB = gK + (size_t)(colbase + srow) * D_DIM + kbyte + sswz * 16;
        __builtin_amdgcn_global_load_lds(
            (const __attribute__((address_space(1))) void*)srcB,
            (__attribute__((address_space(3))) void*)(lds + s * SLOT + 8192 + tid * 16),
            16, 0, 0);
    };

    f32x4 acc[4][2] = {};              // [mi][ni] 16x16 frags (AGPR path)
    l64x2 af[4], bf[2];                // 16B fragments: .x = k-half0, .y = k-half1

    auto read_frag = [&](const char* base, int row) -> l64x2 {
        return *reinterpret_cast<const l64x2*>(
            base + row * 64 + ((kgrp ^ ((row >> 1) & 3)) << 4));
    };

    // prologue: tiles 0,1 staged; publish tile 0 (leave tile 1's 2 in flight)
    stage_all(0); stage_all(1);
    VMCNT(2); BAR();

    for (int t = 0; t < NT; ++t) {
        const int s = t % 3;
        const char* Ab = lds + s * SLOT;
        const char* Bb = Ab + 8192;
#pragma unroll
        for (int mi = 0; mi < 4; ++mi)
            af[mi] = read_frag(Ab, wr * 64 + mi * 16 + (lane & 15));
#pragma unroll
        for (int ni = 0; ni < 2; ++ni)
            bf[ni] = read_frag(Bb, wc * 32 + ni * 16 + (lane & 15));
        if (t + 2 < NT) stage_all(t + 2);               // early prefetch issue
        __builtin_amdgcn_s_setprio(1);
#pragma unroll
        for (int mi = 0; mi < 4; ++mi)
#pragma unroll
            for (int ni = 0; ni < 2; ++ni)
                acc[mi][ni] = __builtin_amdgcn_mfma_f32_16x16x32_fp8_fp8(
                    af[mi].x, bf[ni].x, acc[mi][ni], 0, 0, 0);
        __builtin_amdgcn_s_setprio(0);
        if (t < NT - 1) {
            LGKM0();                                    // drain own reads pre-BAR
            if (t < NT - 2) { VMCNT(2); } else { VMCNT(0); }
            BAR();                                      // publish tile t+1
        }
        __builtin_amdgcn_s_setprio(1);
#pragma unroll
        for (int mi = 0; mi < 4; ++mi)
#pragma unroll
            for (int ni = 0; ni < 2; ++ni)
                acc[mi][ni] = __builtin_amdgcn_mfma_f32_16x16x32_fp8_fp8(
                    af[mi].y, bf[ni].y, acc[mi][ni], 0, 0, 0);
        __builtin_amdgcn_s_setprio(0);
    }

    // Epilogue. C-frag: col = lane&15, row = (lane>>4)*4 + reg.
    float colpart[2] = {0.0f, 0.0f};
#pragma unroll
    for (int mi = 0; mi < 4; ++mi) {
#pragma unroll
        for (int reg = 0; reg < 4; ++reg) {
            const int grow = rowbase + wr * 64 + mi * 16 + ((lane >> 4) << 2) + reg;
            float rowpart = 0.0f;
#pragma unroll
            for (int ni = 0; ni < 2; ++ni) {
                const int gcol = colbase + wc * 32 + ni * 16 + (lane & 15);
                float e = __expf(acc[mi][ni][reg] * EXP_SCALE);
                if (diag && grow == gcol) e = 0.0f;
                rowpart += e;
                colpart[ni] += e;
            }
#pragma unroll
            for (int off = 1; off < 16; off <<= 1)
                rowpart += __shfl_xor(rowpart, off, 64);
            if ((lane & 15) == 0) atomicAdd(&rowsum[grow], rowpart);
        }
    }
    if (!diag) {
#pragma unroll
        for (int ni = 0; ni < 2; ++ni) {
            float cp = colpart[ni];
            cp += __shfl_xor(cp, 16, 64);
            cp += __shfl_xor(cp, 32, 64);
            if (lane < 16)
                atomicAdd(&rowsum[colbase + wc * 32 + ni * 16 + lane], cp);
        }
    }
}

// ---- Kernel C: loss = mean(log(denom) - pos/tau) ---------------------------
__global__ __launch_bounds__(256)
void loss_kernel(const float* __restrict__ rowsum, const float* __restrict__ pos,
                 float* __restrict__ out, int n_total, int n_half) {
    const int t = threadIdx.x;
    float acc = 0.0f;
    for (int r = t; r < n_total; r += 256) {
        const int pi = (r < n_half) ? r : (r - n_half);
        acc += logf(rowsum[r]) - TAU_INV * pos[pi];
    }
    acc = wave_reduce_add(acc);
    __shared__ float ws4[4];
    if ((t & 63) == 0) ws4[t >> 6] = acc;
    __syncthreads();
    if (t == 0) out[0] = (ws4[0] + ws4[1] + ws4[2] + ws4[3]) / (float)n_total;
}

extern "C" void kernel_launch(void* const* d_in, const int* in_sizes, int n_in,
                              void* d_out, int out_size, void* d_ws, size_t ws_size,
                              hipStream_t stream) {
    const float* zi = (const float*)d_in[0];
    const float* zj = (const float*)d_in[1];
    float* out = (float*)d_out;

    const int n_half  = in_sizes[0] / D_DIM;   // 4096
    const int n_total = 2 * n_half;            // 8192

    char* ws = (char*)d_ws;
    unsigned int* Kf = (unsigned int*)ws;                 // 8192 x 1024 fp8 = 8 MB
    size_t off = (size_t)n_total * D_DIM;
    float* rowsum = (float*)(ws + off); off += (size_t)n_total * 4;
    float* pos    = (float*)(ws + off); off += (size_t)n_half * 4;

    norm_pos_kernel<<<n_half, 256, 0, stream>>>(zi, zj, Kf, rowsum, pos, n_half);

    // triangular 128x128 tiles: 64*65/2 = 2080 blocks
    simclr_gemm_kernel<<<2080, 512, 0, stream>>>((const unsigned char*)Kf,
                                                 rowsum, n_total);

    loss_kernel<<<1, 256, 0, stream>>>(rowsum, pos, out, n_total, n_half);
}

// Round 17
// 88.869 us; speedup vs baseline: 1.3980x; 1.3980x over previous
//
#include <hip/hip_runtime.h>
#include <hip/hip_bf16.h>
#include <cstdint>
#include <math.h>

#define D_DIM 1024
#define TAU_INV 10.0f
// K stored as e4m3(64 * k_hat): acc = 4096 * sim -> exp(acc * TAU_INV/4096)
#define EXP_SCALE (TAU_INV / 4096.0f)
#define BK 64                  // 64 fp8 = 64 B per row chunk
#define NT (D_DIM / BK)        // 16 K-tiles
#define BM 128                 // tile rows (128-row bands, 64 of them)
#define BN 256                 // tile cols (256-col bands, 32 of them)
#define SLOT 24576             // ring slot: A 8K + B 16K

typedef float f32x4 __attribute__((ext_vector_type(4)));
typedef long  l64x2 __attribute__((ext_vector_type(2)));

#define VMCNT(n) asm volatile("s_waitcnt vmcnt(" #n ")" ::: "memory")
#define LGKM0()  asm volatile("s_waitcnt lgkmcnt(0)" ::: "memory")
#define BAR() do { asm volatile("" ::: "memory"); \
                   __builtin_amdgcn_s_barrier();  \
                   asm volatile("" ::: "memory"); } while (0)

__device__ __forceinline__ float wave_reduce_add(float v) {
#pragma unroll
    for (int off = 32; off > 0; off >>= 1) v += __shfl_xor(v, off, 64);
    return v;
}

// ---- Kernel A (fused): normalize -> fp8 K (x64 pre-scale, INTERLEAVED),
//      positives, zero rowsum.
// Interleaved row layout (R14-verified): within each 64B K-tile chunk, 8B
// chunks ordered [g0h0][g0h1]...[g3h1] so a GEMM lane's full K=64 fragment is
// one contiguous 16B slot. Thread t (logical k = 4t..4t+3) -> physical word
// w = (t>>4)*16 + ((t>>1)&3)*4 + ((t>>3)&1)*2 + (t&1).
__global__ __launch_bounds__(256)
void norm_pos_kernel(const float* __restrict__ zi, const float* __restrict__ zj,
                     unsigned int* __restrict__ Kf, float* __restrict__ rowsum,
                     float* __restrict__ pos, int n_half) {
    const int i = blockIdx.x;
    const int t = threadIdx.x;                 // 256 threads x 4 floats = 1024
    float4 a = reinterpret_cast<const float4*>(zi + (size_t)i * D_DIM)[t];
    float4 b = reinterpret_cast<const float4*>(zj + (size_t)i * D_DIM)[t];
    float ssa = a.x*a.x + a.y*a.y + a.z*a.z + a.w*a.w;
    float ssb = b.x*b.x + b.y*b.y + b.z*b.z + b.w*b.w;
    float dab = a.x*b.x + a.y*b.y + a.z*b.z + a.w*b.w;
    ssa = wave_reduce_add(ssa);
    ssb = wave_reduce_add(ssb);
    dab = wave_reduce_add(dab);
    __shared__ float wsa[4], wsb[4], wsd[4];
    if ((t & 63) == 0) { wsa[t>>6] = ssa; wsb[t>>6] = ssb; wsd[t>>6] = dab; }
    __syncthreads();
    const float inva = 1.0f / sqrtf(wsa[0] + wsa[1] + wsa[2] + wsa[3]);
    const float invb = 1.0f / sqrtf(wsb[0] + wsb[1] + wsb[2] + wsb[3]);
    const float sa = inva * 64.0f;             // x64: keeps e4m3 in normal range
    const float sb = invb * 64.0f;
    unsigned int ua = 0, ub = 0;
    ua = __builtin_amdgcn_cvt_pk_fp8_f32(a.x * sa, a.y * sa, ua, false);
    ua = __builtin_amdgcn_cvt_pk_fp8_f32(a.z * sa, a.w * sa, ua, true);
    ub = __builtin_amdgcn_cvt_pk_fp8_f32(b.x * sb, b.y * sb, ub, false);
    ub = __builtin_amdgcn_cvt_pk_fp8_f32(b.z * sb, b.w * sb, ub, true);
    const int w = (t >> 4) * 16 + ((t >> 1) & 3) * 4 + ((t >> 3) & 1) * 2 + (t & 1);
    Kf[(size_t)i * 256 + w] = ua;                          // 1024 B row = 256 u32
    Kf[(size_t)(i + n_half) * 256 + w] = ub;
    if (t == 0) {
        pos[i] = (wsd[0] + wsd[1] + wsd[2] + wsd[3]) * inva * invb;
        rowsum[i] = 0.0f;
        rowsum[i + n_half] = 0.0f;
    }
}

// ---- Kernel B: 128x256 triangular tiles of S, fp8 plain MFMA ----------------
// Rounds fix: by in [0,64) 128-row bands, bx in [ceil(by/2), 32) 256-col
// bands -> sum(32 - ceil(by/2)) = EXACTLY 1024 uniform jobs on 512 slots
// (2 blocks/CU) = exactly 2 dispatch generations (R14 had 1056 -> 3).
// Per-wave geometry/schedule = R14 verbatim (the proven optimum): 8 waves
// (2M x 4N) of 64x64 = acc[4][4]; 8 b128 frag reads : 32 MFMA per K-tile;
// ring-3 LDS 72 KiB -> 2 blocks/CU; 1 barrier/K-tile; counted VMCNT(3)
// (3 gloads/thread/K-tile: A 1 issue + B 2); dist-2 prefetch; interleaved-fp8
// 16B fragments at the 0-conflict pattern row*64 + ((kgrp^((row>>1)&3))<<4).
// Diagonal handling: tile is "diag" iff by even and bx == by>>1; then cols
// [0,128) of the tile form the symmetric square containing the diagonal ->
// waves wc<2: row-reduce only + zero exact diag; waves wc>=2 and all waves of
// non-diag tiles: row+col dual reduction (strictly-upper region, counted once).
__global__ __launch_bounds__(512, 4)
void simclr_gemm_kernel(const unsigned char* __restrict__ Kmat,
                        float* __restrict__ rowsum, int n_total) {
    __shared__ char lds[73728];

    const int tid  = threadIdx.x;
    const int lane = tid & 63;
    const int wave = tid >> 6;          // 0..7
    const int wr = wave >> 2;           // 0..1  (A rows wr*64)
    const int wc = wave & 3;            // 0..3  (B cols wc*64)
    const int kgrp = lane >> 4;         // 16B fragment slot within 64B row

    // bijective XCD swizzle: nwg = 1024 = 8 * 128
    const int wg = (blockIdx.x & 7) * 128 + (blockIdx.x >> 3);

    // decode wg -> (by, bx): by in [0,64), bx in [ceil(by/2), 32)
    int by = 0, start = 0;
    while (wg >= start + (32 - ((by + 1) >> 1))) {
        start += 32 - ((by + 1) >> 1);
        ++by;
    }
    const int bx = ((by + 1) >> 1) + (wg - start);
    const bool diag = (((by & 1) == 0) && (bx == (by >> 1)));
    const int rowbase = by * BM;
    const int colbase = bx * BN;
    // this wave's columns: dual-reduce unless in the diag tile's left half
    const bool dual = (!diag) || (wc >= 2);
    const bool zdiag = diag && (wc < 2);

    const char* gK = reinterpret_cast<const char*>(Kmat);
    const int srow = tid >> 2;                          // 0..127 per 8KB issue
    const int sswz = (tid & 3) ^ ((srow >> 1) & 3);     // inverse-swizzled slot

    // stage full K-tile tt into ring slot tt%3: A 1 issue + B 2 issues
    auto stage_all = [&](int tt) {
        const int s = tt % 3;
        const size_t kbyte = (size_t)tt * BK;           // 64 B per row chunk
        const char* srcA = gK + (size_t)(rowbase + srow) * D_DIM + kbyte + sswz * 16;
        __builtin_amdgcn_global_load_lds(
            (const __attribute__((address_space(1))) void*)srcA,
            (__attribute__((address_space(3))) void*)(lds + s * SLOT + tid * 16),
            16, 0, 0);
        char* dstB = lds + s * SLOT + 8192 + tid * 16;
#pragma unroll
        for (int i = 0; i < 2; ++i) {
            const int row = i * 128 + srow;
            const char* srcB = gK + (size_t)(colbase + row) * D_DIM + kbyte + sswz * 16;
            __builtin_amdgcn_global_load_lds(
                (const __attribute__((address_space(1))) void*)srcB,
                (__attribute__((address_space(3))) void*)(dstB + i * 8192),
                16, 0, 0);
        }
    };

    f32x4 acc[4][4] = {};              // [mi][ni] 16x16 frags (AGPR path)
    l64x2 af[4], bf[4];                // 16B fragments: .x = k-half0, .y = k-half1

    auto read_frag = [&](const char* base, int row) -> l64x2 {
        return *reinterpret_cast<const l64x2*>(
            base + row * 64 + ((kgrp ^ ((row >> 1) & 3)) << 4));
    };

    // prologue: tiles 0,1 staged; publish tile 0 (leave tile 1's 3 in flight)
    stage_all(0); stage_all(1);
    VMCNT(3); BAR();

    for (int t = 0; t < NT; ++t) {
        const int s = t % 3;
        const char* Ab = lds + s * SLOT;
        const char* Bb = Ab + 8192;
#pragma unroll
        for (int mi = 0; mi < 4; ++mi)
            af[mi] = read_frag(Ab, wr * 64 + mi * 16 + (lane & 15));
#pragma unroll
        for (int ni = 0; ni < 4; ++ni)
            bf[ni] = read_frag(Bb, wc * 64 + ni * 16 + (lane & 15));
        if (t + 2 < NT) stage_all(t + 2);               // early prefetch issue
        __builtin_amdgcn_s_setprio(1);
#pragma unroll
        for (int mi = 0; mi < 4; ++mi)
#pragma unroll
            for (int ni = 0; ni < 4; ++ni)
                acc[mi][ni] = __builtin_amdgcn_mfma_f32_16x16x32_fp8_fp8(
                    af[mi].x, bf[ni].x, acc[mi][ni], 0, 0, 0);
        __builtin_amdgcn_s_setprio(0);
        if (t < NT - 1) {
            LGKM0();                                    // drain own reads pre-BAR
            if (t < NT - 2) { VMCNT(3); } else { VMCNT(0); }
            BAR();                                      // publish tile t+1
        }
        __builtin_amdgcn_s_setprio(1);
#pragma unroll
        for (int mi = 0; mi < 4; ++mi)
#pragma unroll
            for (int ni = 0; ni < 4; ++ni)
                acc[mi][ni] = __builtin_amdgcn_mfma_f32_16x16x32_fp8_fp8(
                    af[mi].y, bf[ni].y, acc[mi][ni], 0, 0, 0);
        __builtin_amdgcn_s_setprio(0);
    }

    // Epilogue. C-frag: col = lane&15, row = (lane>>4)*4 + reg.
    float colpart[4] = {0.0f, 0.0f, 0.0f, 0.0f};
#pragma unroll
    for (int mi = 0; mi < 4; ++mi) {
#pragma unroll
        for (int reg = 0; reg < 4; ++reg) {
            const int grow = rowbase + wr * 64 + mi * 16 + ((lane >> 4) << 2) + reg;
            float rowpart = 0.0f;
#pragma unroll
            for (int ni = 0; ni < 4; ++ni) {
                const int gcol = colbase + wc * 64 + ni * 16 + (lane & 15);
                float e = __expf(acc[mi][ni][reg] * EXP_SCALE);
                if (zdiag && grow == gcol) e = 0.0f;
                rowpart += e;
                colpart[ni] += e;
            }
#pragma unroll
            for (int off = 1; off < 16; off <<= 1)
                rowpart += __shfl_xor(rowpart, off, 64);
            if ((lane & 15) == 0) atomicAdd(&rowsum[grow], rowpart);
        }
    }
    if (dual) {
#pragma unroll
        for (int ni = 0; ni < 4; ++ni) {
            float cp = colpart[ni];
            cp += __shfl_xor(cp, 16, 64);
            cp += __shfl_xor(cp, 32, 64);
            if (lane < 16)
                atomicAdd(&rowsum[colbase + wc * 64 + ni * 16 + lane], cp);
        }
    }
}

// ---- Kernel C: loss = mean(log(denom) - pos/tau) ---------------------------
__global__ __launch_bounds__(256)
void loss_kernel(const float* __restrict__ rowsum, const float* __restrict__ pos,
                 float* __restrict__ out, int n_total, int n_half) {
    const int t = threadIdx.x;
    float acc = 0.0f;
    for (int r = t; r < n_total; r += 256) {
        const int pi = (r < n_half) ? r : (r - n_half);
        acc += logf(rowsum[r]) - TAU_INV * pos[pi];
    }
    acc = wave_reduce_add(acc);
    __shared__ float ws4[4];
    if ((t & 63) == 0) ws4[t >> 6] = acc;
    __syncthreads();
    if (t == 0) out[0] = (ws4[0] + ws4[1] + ws4[2] + ws4[3]) / (float)n_total;
}

extern "C" void kernel_launch(void* const* d_in, const int* in_sizes, int n_in,
                              void* d_out, int out_size, void* d_ws, size_t ws_size,
                              hipStream_t stream) {
    const float* zi = (const float*)d_in[0];
    const float* zj = (const float*)d_in[1];
    float* out = (float*)d_out;

    const int n_half  = in_sizes[0] / D_DIM;   // 4096
    const int n_total = 2 * n_half;            // 8192

    char* ws = (char*)d_ws;
    unsigned int* Kf = (unsigned int*)ws;                 // 8192 x 1024 fp8 = 8 MB
    size_t off = (size_t)n_total * D_DIM;
    float* rowsum = (float*)(ws + off); off += (size_t)n_total * 4;
    float* pos    = (float*)(ws + off); off += (size_t)n_half * 4;

    norm_pos_kernel<<<n_half, 256, 0, stream>>>(zi, zj, Kf, rowsum, pos, n_half);

    // 128x256 triangular tiles: sum_{by=0}^{63} (32 - ceil(by/2)) = 1024 blocks
    simclr_gemm_kernel<<<1024, 512, 0, stream>>>((const unsigned char*)Kf,
                                                 rowsum, n_total);

    loss_kernel<<<1, 256, 0, stream>>>(rowsum, pos, out, n_total, n_half);
}

// Round 18
// 81.934 us; speedup vs baseline: 1.5164x; 1.0846x over previous
//
#include <hip/hip_runtime.h>
#include <hip/hip_bf16.h>
#include <cstdint>
#include <math.h>

#define D_DIM 1024
#define TAU_INV 10.0f
// K stored as e4m3(64 * k_hat): acc = 4096 * sim -> exp(acc * TAU_INV/4096)
#define EXP_SCALE (TAU_INV / 4096.0f)
#define BK 64                  // 64 fp8 = 64 B per row chunk
#define NT (D_DIM / BK)        // 16 K-tiles
#define BM 256                 // tile rows
#define BN 128                 // tile cols
#define SLOT 24576             // ring slot: A 16K + B 8K

typedef float f32x4 __attribute__((ext_vector_type(4)));
typedef long  l64x2 __attribute__((ext_vector_type(2)));

#define VMCNT(n) asm volatile("s_waitcnt vmcnt(" #n ")" ::: "memory")
#define LGKM0()  asm volatile("s_waitcnt lgkmcnt(0)" ::: "memory")
#define BAR() do { asm volatile("" ::: "memory"); \
                   __builtin_amdgcn_s_barrier();  \
                   asm volatile("" ::: "memory"); } while (0)

__device__ __forceinline__ float wave_reduce_add(float v) {
#pragma unroll
    for (int off = 32; off > 0; off >>= 1) v += __shfl_xor(v, off, 64);
    return v;
}

// ---- Kernel A (fused): normalize -> fp8 K (x64 pre-scale, INTERLEAVED),
//      positives, zero rowsum.
// Interleaved row layout (R14-verified): within each 64B K-tile chunk, 8B
// chunks ordered [g0h0][g0h1]...[g3h1] so a GEMM lane's full K=64 fragment is
// one contiguous 16B slot. Thread t (logical k = 4t..4t+3) -> physical word
// w = (t>>4)*16 + ((t>>1)&3)*4 + ((t>>3)&1)*2 + (t&1).
__global__ __launch_bounds__(256)
void norm_pos_kernel(const float* __restrict__ zi, const float* __restrict__ zj,
                     unsigned int* __restrict__ Kf, float* __restrict__ rowsum,
                     float* __restrict__ pos, int n_half) {
    const int i = blockIdx.x;
    const int t = threadIdx.x;                 // 256 threads x 4 floats = 1024
    float4 a = reinterpret_cast<const float4*>(zi + (size_t)i * D_DIM)[t];
    float4 b = reinterpret_cast<const float4*>(zj + (size_t)i * D_DIM)[t];
    float ssa = a.x*a.x + a.y*a.y + a.z*a.z + a.w*a.w;
    float ssb = b.x*b.x + b.y*b.y + b.z*b.z + b.w*b.w;
    float dab = a.x*b.x + a.y*b.y + a.z*b.z + a.w*b.w;
    ssa = wave_reduce_add(ssa);
    ssb = wave_reduce_add(ssb);
    dab = wave_reduce_add(dab);
    __shared__ float wsa[4], wsb[4], wsd[4];
    if ((t & 63) == 0) { wsa[t>>6] = ssa; wsb[t>>6] = ssb; wsd[t>>6] = dab; }
    __syncthreads();
    const float inva = 1.0f / sqrtf(wsa[0] + wsa[1] + wsa[2] + wsa[3]);
    const float invb = 1.0f / sqrtf(wsb[0] + wsb[1] + wsb[2] + wsb[3]);
    const float sa = inva * 64.0f;             // x64: keeps e4m3 in normal range
    const float sb = invb * 64.0f;
    unsigned int ua = 0, ub = 0;
    ua = __builtin_amdgcn_cvt_pk_fp8_f32(a.x * sa, a.y * sa, ua, false);
    ua = __builtin_amdgcn_cvt_pk_fp8_f32(a.z * sa, a.w * sa, ua, true);
    ub = __builtin_amdgcn_cvt_pk_fp8_f32(b.x * sb, b.y * sb, ub, false);
    ub = __builtin_amdgcn_cvt_pk_fp8_f32(b.z * sb, b.w * sb, ub, true);
    const int w = (t >> 4) * 16 + ((t >> 1) & 3) * 4 + ((t >> 3) & 1) * 2 + (t & 1);
    Kf[(size_t)i * 256 + w] = ua;                          // 1024 B row = 256 u32
    Kf[(size_t)(i + n_half) * 256 + w] = ub;
    if (t == 0) {
        pos[i] = (wsd[0] + wsd[1] + wsd[2] + wsd[3]) * inva * invb;
        rowsum[i] = 0.0f;
        rowsum[i + n_half] = 0.0f;
    }
}

// ---- Kernel B: triangular 256x128 tiles of S, fp8 plain MFMA (R14 config) ---
// Empirical optimum of this schedule family (R15 tile-size, R16 wave-size,
// R17 tile-aspect, R8 ring-depth, R5/R6 barrier-count, R11/R12 mfma_scale all
// regressed). 8 waves of 64x64 (acc[4][4] 16x16 frags), 64B LDS rows, ring-3
// LDS 72 KiB -> 2 blocks/CU, 1 barrier/K-tile, counted VMCNT(3), dist-2
// prefetch. Fragment = ONE ds_read_b128 (interleaved-fp8 global layout) at
// the measured-0-conflict pattern row*64 + ((kgrp^((row>>1)&3))<<4).
// Per K-tile: 8 b128 reads up-front, 16 MFMA (k-half lo), {LGKM0;VMCNT;BAR},
// 16 MFMA (k-half hi, regs only).
// diag (bx>>1==by): row-reduction only, exact diagonal zeroed; else row+col.
__global__ __launch_bounds__(512, 4)
void simclr_gemm_kernel(const unsigned char* __restrict__ Kmat,
                        float* __restrict__ rowsum, int n_total) {
    __shared__ char lds[73728];

    const int tid  = threadIdx.x;
    const int lane = tid & 63;
    const int wave = tid >> 6;          // 0..7
    const int wr = wave >> 1;           // 0..3  (A rows wr*64)
    const int wc = wave & 1;            // 0..1  (B cols wc*64)
    const int kgrp = lane >> 4;         // 16B fragment slot within 64B row

    // bijective XCD swizzle: nwg = 1056 = 8 * 132
    const int wg = (blockIdx.x & 7) * 132 + (blockIdx.x >> 3);

    // decode wg -> (by, bx): by in [0,32), bx in [2*by, 64)
    int by = 0, start = 0;
    while (wg >= start + (64 - 2 * by)) { start += 64 - 2 * by; ++by; }
    const int bx = 2 * by + (wg - start);
    const bool diag = ((bx >> 1) == by);
    const int rowbase = by * BM;
    const int colbase = bx * BN;

    const char* gK = reinterpret_cast<const char*>(Kmat);
    const int srow = tid >> 2;                          // 0..127 per 8KB issue
    const int sswz = (tid & 3) ^ ((srow >> 1) & 3);     // inverse-swizzled slot

    // stage full K-tile tt into ring slot tt%3: A 2 issues + B 1 issue
    auto stage_all = [&](int tt) {
        const int s = tt % 3;
        const size_t kbyte = (size_t)tt * BK;           // 64 B per row chunk
        char* dstA = lds + s * SLOT + tid * 16;
        char* dstB = lds + s * SLOT + 16384 + tid * 16;
#pragma unroll
        for (int i = 0; i < 2; ++i) {
            const int row = i * 128 + srow;
            const char* src = gK + (size_t)(rowbase + row) * D_DIM + kbyte + sswz * 16;
            __builtin_amdgcn_global_load_lds(
                (const __attribute__((address_space(1))) void*)src,
                (__attribute__((address_space(3))) void*)(dstA + i * 8192),
                16, 0, 0);
        }
        {
            const char* src = gK + (size_t)(colbase + srow) * D_DIM + kbyte + sswz * 16;
            __builtin_amdgcn_global_load_lds(
                (const __attribute__((address_space(1))) void*)src,
                (__attribute__((address_space(3))) void*)dstB,
                16, 0, 0);
        }
    };

    f32x4 acc[4][4] = {};              // [mi][ni] 16x16 frags (AGPR path)
    l64x2 af[4], bf[4];                // 16B fragments: .x = k-half0, .y = k-half1

    auto read_frag = [&](const char* base, int row) -> l64x2 {
        return *reinterpret_cast<const l64x2*>(
            base + row * 64 + ((kgrp ^ ((row >> 1) & 3)) << 4));
    };

    // prologue: tiles 0,1 staged; publish tile 0 (leave tile 1's 3 in flight)
    stage_all(0); stage_all(1);
    VMCNT(3); BAR();

    for (int t = 0; t < NT; ++t) {
        const int s = t % 3;
        const char* Ab = lds + s * SLOT;
        const char* Bb = Ab + 16384;
#pragma unroll
        for (int mi = 0; mi < 4; ++mi)
            af[mi] = read_frag(Ab, wr * 64 + mi * 16 + (lane & 15));
#pragma unroll
        for (int ni = 0; ni < 4; ++ni)
            bf[ni] = read_frag(Bb, wc * 64 + ni * 16 + (lane & 15));
        if (t + 2 < NT) stage_all(t + 2);               // early prefetch issue
        __builtin_amdgcn_s_setprio(1);
#pragma unroll
        for (int mi = 0; mi < 4; ++mi)
#pragma unroll
            for (int ni = 0; ni < 4; ++ni)
                acc[mi][ni] = __builtin_amdgcn_mfma_f32_16x16x32_fp8_fp8(
                    af[mi].x, bf[ni].x, acc[mi][ni], 0, 0, 0);
        __builtin_amdgcn_s_setprio(0);
        if (t < NT - 1) {
            LGKM0();                                    // drain own reads pre-BAR
            if (t < NT - 2) { VMCNT(3); } else { VMCNT(0); }
            BAR();                                      // publish tile t+1
        }
        __builtin_amdgcn_s_setprio(1);
#pragma unroll
        for (int mi = 0; mi < 4; ++mi)
#pragma unroll
            for (int ni = 0; ni < 4; ++ni)
                acc[mi][ni] = __builtin_amdgcn_mfma_f32_16x16x32_fp8_fp8(
                    af[mi].y, bf[ni].y, acc[mi][ni], 0, 0, 0);
        __builtin_amdgcn_s_setprio(0);
    }

    // Epilogue. C-frag: col = lane&15, row = (lane>>4)*4 + reg.
    float colpart[4] = {0.0f, 0.0f, 0.0f, 0.0f};
#pragma unroll
    for (int mi = 0; mi < 4; ++mi) {
#pragma unroll
        for (int reg = 0; reg < 4; ++reg) {
            const int grow = rowbase + wr * 64 + mi * 16 + ((lane >> 4) << 2) + reg;
            float rowpart = 0.0f;
#pragma unroll
            for (int ni = 0; ni < 4; ++ni) {
                const int gcol = colbase + wc * 64 + ni * 16 + (lane & 15);
                float e = __expf(acc[mi][ni][reg] * EXP_SCALE);
                if (diag && grow == gcol) e = 0.0f;
                rowpart += e;
                colpart[ni] += e;
            }
#pragma unroll
            for (int off = 1; off < 16; off <<= 1)
                rowpart += __shfl_xor(rowpart, off, 64);
            if ((lane & 15) == 0) atomicAdd(&rowsum[grow], rowpart);
        }
    }
    if (!diag) {
#pragma unroll
        for (int ni = 0; ni < 4; ++ni) {
            float cp = colpart[ni];
            cp += __shfl_xor(cp, 16, 64);
            cp += __shfl_xor(cp, 32, 64);
            if (lane < 16)
                atomicAdd(&rowsum[colbase + wc * 64 + ni * 16 + lane], cp);
        }
    }
}

// ---- Kernel C: loss = mean(log(denom) - pos/tau) ---------------------------
__global__ __launch_bounds__(256)
void loss_kernel(const float* __restrict__ rowsum, const float* __restrict__ pos,
                 float* __restrict__ out, int n_total, int n_half) {
    const int t = threadIdx.x;
    float acc = 0.0f;
    for (int r = t; r < n_total; r += 256) {
        const int pi = (r < n_half) ? r : (r - n_half);
        acc += logf(rowsum[r]) - TAU_INV * pos[pi];
    }
    acc = wave_reduce_add(acc);
    __shared__ float ws4[4];
    if ((t & 63) == 0) ws4[t >> 6] = acc;
    __syncthreads();
    if (t == 0) out[0] = (ws4[0] + ws4[1] + ws4[2] + ws4[3]) / (float)n_total;
}

extern "C" void kernel_launch(void* const* d_in, const int* in_sizes, int n_in,
                              void* d_out, int out_size, void* d_ws, size_t ws_size,
                              hipStream_t stream) {
    const float* zi = (const float*)d_in[0];
    const float* zj = (const float*)d_in[1];
    float* out = (float*)d_out;

    const int n_half  = in_sizes[0] / D_DIM;   // 4096
    const int n_total = 2 * n_half;            // 8192

    char* ws = (char*)d_ws;
    unsigned int* Kf = (unsigned int*)ws;                 // 8192 x 1024 fp8 = 8 MB
    size_t off = (size_t)n_total * D_DIM;
    float* rowsum = (float*)(ws + off); off += (size_t)n_total * 4;
    float* pos    = (float*)(ws + off); off += (size_t)n_half * 4;

    norm_pos_kernel<<<n_half, 256, 0, stream>>>(zi, zj, Kf, rowsum, pos, n_half);

    // triangular 256x128 tiles: sum_{by=0}^{31} (64 - 2*by) = 1056 blocks
    simclr_gemm_kernel<<<1056, 512, 0, stream>>>((const unsigned char*)Kf,
                                                 rowsum, n_total);

    loss_kernel<<<1, 256, 0, stream>>>(rowsum, pos, out, n_total, n_half);
}